// Round 1
// baseline (35.709 us; speedup 1.0000x reference)
//
#include <hip/hip_runtime.h>

// Problem constants (match the reference setup_inputs()):
//   items:        [B=16384, L=50] int32, padded with -1
//   item_factors: [N_ITEMS=100000, D=128] float32
//   out:          [B] float32 = sigmoid(sum_d(prod_l emb[l, d]))
#define MF_L 50
#define MF_D 128

__global__ __launch_bounds__(MF_D) void newmf_prod_reduce(
    const int* __restrict__ items,
    const float* __restrict__ factors,
    float* __restrict__ out)
{
    const int row = blockIdx.x;
    const int d   = threadIdx.x;          // 0..127, one factor per thread

    __shared__ int s_items[MF_L];
    if (d < MF_L) s_items[d] = items[row * MF_L + d];
    __syncthreads();

    // Two independent product chains; padded (-1) entries contribute 1.0.
    // The (it >= 0) branch is uniform across the whole block (same item id),
    // so there is no divergence; the gather is a coalesced 512B segment.
    float p0 = 1.0f, p1 = 1.0f;
    #pragma unroll 5
    for (int j = 0; j < MF_L; j += 2) {
        const int i0 = s_items[j];
        const int i1 = s_items[j + 1];
        const float f0 = (i0 >= 0) ? factors[(size_t)i0 * MF_D + d] : 1.0f;
        const float f1 = (i1 >= 0) ? factors[(size_t)i1 * MF_D + d] : 1.0f;
        p0 *= f0;
        p1 *= f1;
    }
    float v = p0 * p1;

    // Reduce across the 64-lane wave (butterfly), then across the 2 waves.
    #pragma unroll
    for (int off = 1; off < 64; off <<= 1)
        v += __shfl_xor(v, off, 64);

    __shared__ float s_part[2];
    if ((threadIdx.x & 63) == 0) s_part[threadIdx.x >> 6] = v;
    __syncthreads();

    if (threadIdx.x == 0) {
        const float s = s_part[0] + s_part[1];
        out[row] = 1.0f / (1.0f + __expf(-s));
    }
}

extern "C" void kernel_launch(void* const* d_in, const int* in_sizes, int n_in,
                              void* d_out, int out_size, void* d_ws, size_t ws_size,
                              hipStream_t stream)
{
    const int*   items   = (const int*)d_in[0];     // [B, L] int32
    const float* factors = (const float*)d_in[1];   // [N_ITEMS, D] float32
    float*       out     = (float*)d_out;           // [B] float32

    const int B = in_sizes[0] / MF_L;               // 16384

    newmf_prod_reduce<<<B, MF_D, 0, stream>>>(items, factors, out);
}